// Round 4
// baseline (401.464 us; speedup 1.0000x reference)
//
#include <hip/hip_runtime.h>
#include <hip/hip_bf16.h>
#include <cstddef>

// Problem constants
#define B_  2
#define LV_ 1024
#define LE_ 64
#define S_TOT 1088          // LV+LE
#define DV_ 2560
#define DE_ 1920
#define H_  32
#define KVH_ 8
#define DH_ 128
#define HD_ 4096            // H*DH
#define KVD_ 1024           // KVH*DH

typedef short short8 __attribute__((ext_vector_type(8)));
typedef float f32x4 __attribute__((ext_vector_type(4)));

typedef __hip_bfloat16 bf16;

__device__ inline float b2f(bf16 h) { return __bfloat162float(h); }
__device__ inline bf16 f2b(float f) { return __float2bfloat16(f); }

// ---------------- Workspace layout (byte offsets) ----------------
#define OFF_HVB   0ul
#define OFF_WKVT  10485760ul
#define OFF_HEB   20971520ul
#define OFF_WQKVT 21463040ul
#define OFF_QE    45056000ul
#define OFF_KBUF  46104576ul
#define OFF_VBUF  50561024ul
#define OFF_AO    59473920ul
#define OFF_P1    0ul        // aliases hv_b+WkvT (dead after big gemm)
#define OFF_WOT   0ul        // aliases part1 (dead after reduce1)
#define OFF_P2    21463040ul // aliases WqkvT (dead after splitk1)

#define NSPLIT1 6
#define NSPLIT2 16

// ---------------- RMSNorm -> bf16 ----------------
__global__ __launch_bounds__(256) void rmsnorm_bf16(
    const float* __restrict__ x, const float* __restrict__ w,
    bf16* __restrict__ out, int D) {
  int row = blockIdx.x;
  const float4* x4 = (const float4*)(x + (size_t)row * D);
  const float4* w4 = (const float4*)w;
  int D4 = D >> 2;
  float ss = 0.f;
  for (int i = threadIdx.x; i < D4; i += 256) {
    float4 v = x4[i];
    ss += v.x * v.x + v.y * v.y + v.z * v.z + v.w * v.w;
  }
  __shared__ float red[256];
  red[threadIdx.x] = ss; __syncthreads();
  for (int s = 128; s > 0; s >>= 1) {
    if (threadIdx.x < s) red[threadIdx.x] += red[threadIdx.x + s];
    __syncthreads();
  }
  float inv = rsqrtf(red[0] / (float)D + 1e-6f);
  ushort4* o4 = (ushort4*)(out + (size_t)row * D);
  for (int i = threadIdx.x; i < D4; i += 256) {
    float4 v = x4[i], wv = w4[i];
    bf16 a = f2b(v.x * inv * wv.x), b = f2b(v.y * inv * wv.y);
    bf16 c = f2b(v.z * inv * wv.z), d = f2b(v.w * inv * wv.w);
    ushort4 o;
    o.x = *(ushort*)&a; o.y = *(ushort*)&b; o.z = *(ushort*)&c; o.w = *(ushort*)&d;
    o4[i] = o;
  }
}

// ---------------- Transpose + convert: W (KxN f32) -> Wt (NxK bf16) ----------------
__global__ __launch_bounds__(256) void tconv(
    const float* __restrict__ W, bf16* __restrict__ Wt,
    int K, int N, int n_off) {
  __shared__ float t[64][65];
  int n0 = blockIdx.x * 64, k0 = blockIdx.y * 64;
  int tid = threadIdx.x;
  int c = tid & 63, r4 = tid >> 6;
#pragma unroll 4
  for (int it = 0; it < 16; ++it) {
    int k = it * 4 + r4;
    t[k][c] = W[(size_t)(k0 + k) * N + n0 + c];
  }
  __syncthreads();
#pragma unroll 4
  for (int it = 0; it < 16; ++it) {
    int n = it * 4 + r4;
    Wt[(size_t)(n_off + n0 + n) * K + k0 + c] = f2b(t[c][n]);
  }
}

// ---------------- bf16 MFMA GEMM (big): C = A(MxK) * Bt(NxK)^T ----------------
__global__ __launch_bounds__(256) void gemm_mfma(
    const bf16* __restrict__ A, const bf16* __restrict__ Bt,
    int M, int N, int K,
    bf16* __restrict__ p_k, bf16* __restrict__ p_v) {
  __shared__ ushort As[128][40];
  __shared__ ushort Bs[128][40];
  int tid = threadIdx.x;
  int lane = tid & 63, wid = tid >> 6;
  int wm = (wid >> 1) * 64, wn = (wid & 1) * 64;
  int m0 = blockIdx.y * 128, n0 = blockIdx.x * 128;
  int lrow = lane & 15, quad = lane >> 4;

  f32x4 acc[4][4] = {};

  int ar = tid >> 2;            // 0..63
  int ac = (tid & 3) * 8;       // 0,8,16,24
  const ushort* Aptr = (const ushort*)A + (size_t)(m0 + ar) * K + ac;
  const ushort* Bptr = (const ushort*)Bt + (size_t)(n0 + ar) * K + ac;

  for (int k0 = 0; k0 < K; k0 += 32) {
    short8 a0 = *(const short8*)(Aptr + k0);
    short8 a1 = *(const short8*)(Aptr + (size_t)64 * K + k0);
    short8 b0 = *(const short8*)(Bptr + k0);
    short8 b1 = *(const short8*)(Bptr + (size_t)64 * K + k0);
    __syncthreads();
    *(short8*)&As[ar][ac] = a0;
    *(short8*)&As[64 + ar][ac] = a1;
    *(short8*)&Bs[ar][ac] = b0;
    *(short8*)&Bs[64 + ar][ac] = b1;
    __syncthreads();
    short8 af[4], bfr[4];
#pragma unroll
    for (int i = 0; i < 4; ++i) {
      af[i]  = *(const short8*)&As[wm + i * 16 + lrow][quad * 8];
      bfr[i] = *(const short8*)&Bs[wn + i * 16 + lrow][quad * 8];
    }
#pragma unroll
    for (int i = 0; i < 4; ++i)
#pragma unroll
      for (int j = 0; j < 4; ++j)
        acc[i][j] = __builtin_amdgcn_mfma_f32_16x16x32_bf16(af[i], bfr[j], acc[i][j], 0, 0, 0);
  }

#pragma unroll
  for (int i = 0; i < 4; ++i) {
    int gm_base = m0 + wm + i * 16 + quad * 4;
#pragma unroll
    for (int j = 0; j < 4; ++j) {
      int gn = n0 + wn + j * 16 + lrow;
#pragma unroll
      for (int r = 0; r < 4; ++r) {
        int m = gm_base + r;
        float v = acc[i][j][r];
        int b = m >> 10, s = m & 1023;
        size_t row = (size_t)(b * S_TOT + s);
        if (gn < 1024) p_k[row * KVD_ + gn] = f2b(v);
        else           p_v[row * KVD_ + (gn - 1024)] = f2b(v);
      }
    }
  }
}

// ---------------- Split-K MFMA GEMM for M=128 skinny GEMMs ----------------
__global__ __launch_bounds__(256) void gemm_splitk(
    const bf16* __restrict__ A, const bf16* __restrict__ Bt,
    int N, int K_full, int Kc, float* __restrict__ partial) {
  __shared__ ushort As[128][40];
  __shared__ ushort Bs[128][40];
  int tid = threadIdx.x;
  int lane = tid & 63, wid = tid >> 6;
  int wm = (wid >> 1) * 64, wn = (wid & 1) * 64;
  int n0 = blockIdx.x * 128;
  int k_beg = blockIdx.y * Kc, k_end = k_beg + Kc;
  int lrow = lane & 15, quad = lane >> 4;

  f32x4 acc[4][4] = {};

  int ar = tid >> 2;
  int ac = (tid & 3) * 8;
  const ushort* Aptr = (const ushort*)A + (size_t)ar * K_full + ac;
  const ushort* Bptr = (const ushort*)Bt + (size_t)(n0 + ar) * K_full + ac;

  for (int k0 = k_beg; k0 < k_end; k0 += 32) {
    short8 a0 = *(const short8*)(Aptr + k0);
    short8 a1 = *(const short8*)(Aptr + (size_t)64 * K_full + k0);
    short8 b0 = *(const short8*)(Bptr + k0);
    short8 b1 = *(const short8*)(Bptr + (size_t)64 * K_full + k0);
    __syncthreads();
    *(short8*)&As[ar][ac] = a0;
    *(short8*)&As[64 + ar][ac] = a1;
    *(short8*)&Bs[ar][ac] = b0;
    *(short8*)&Bs[64 + ar][ac] = b1;
    __syncthreads();
    short8 af[4], bfr[4];
#pragma unroll
    for (int i = 0; i < 4; ++i) {
      af[i]  = *(const short8*)&As[wm + i * 16 + lrow][quad * 8];
      bfr[i] = *(const short8*)&Bs[wn + i * 16 + lrow][quad * 8];
    }
#pragma unroll
    for (int i = 0; i < 4; ++i)
#pragma unroll
      for (int j = 0; j < 4; ++j)
        acc[i][j] = __builtin_amdgcn_mfma_f32_16x16x32_bf16(af[i], bfr[j], acc[i][j], 0, 0, 0);
  }

  float* pbase = partial + (size_t)blockIdx.y * 128 * N;
#pragma unroll
  for (int i = 0; i < 4; ++i) {
    int m_base = wm + i * 16 + quad * 4;
#pragma unroll
    for (int j = 0; j < 4; ++j) {
      int gn = n0 + wn + j * 16 + lrow;
#pragma unroll
      for (int r = 0; r < 4; ++r)
        pbase[(size_t)(m_base + r) * N + gn] = acc[i][j][r];
    }
  }
}

// ---------------- Reduce split-K partials: expert QKV (N=6144) ----------------
__global__ __launch_bounds__(256) void reduce_qkv(
    const float* __restrict__ partial, bf16* __restrict__ qe,
    bf16* __restrict__ kbuf, bf16* __restrict__ vbuf) {
  int idx = (blockIdx.x * 256 + threadIdx.x) * 4;   // over 128*6144
  int m = idx / 6144, n = idx % 6144;
  f32x4 s = {};
#pragma unroll
  for (int sp = 0; sp < NSPLIT1; ++sp) {
    const f32x4 v = *(const f32x4*)(partial + (size_t)sp * 128 * 6144 + idx);
    s += v;
  }
  ushort4 o;
  bf16 h0 = f2b(s[0]), h1 = f2b(s[1]), h2 = f2b(s[2]), h3 = f2b(s[3]);
  o.x = *(ushort*)&h0; o.y = *(ushort*)&h1; o.z = *(ushort*)&h2; o.w = *(ushort*)&h3;
  int b = m >> 6, l = m & 63;
  if (n < 4096) {
    *(ushort4*)((ushort*)qe + (size_t)m * HD_ + n) = o;
  } else {
    size_t row = (size_t)(b * S_TOT + LV_ + l);
    if (n < 5120) *(ushort4*)((ushort*)kbuf + row * KVD_ + (n - 4096)) = o;
    else          *(ushort4*)((ushort*)vbuf + row * KVD_ + (n - 5120)) = o;
  }
}

// ---------------- Reduce split-K partials + residual: output (N=1920) ----------------
__global__ __launch_bounds__(256) void reduce_out(
    const float* __restrict__ partial, const float* __restrict__ residual,
    float* __restrict__ out) {
  int idx = (blockIdx.x * 256 + threadIdx.x) * 4;   // over 128*1920
  f32x4 s = *(const f32x4*)(residual + idx);
#pragma unroll
  for (int sp = 0; sp < NSPLIT2; ++sp) {
    const f32x4 v = *(const f32x4*)(partial + (size_t)sp * 128 * 1920 + idx);
    s += v;
  }
  *(f32x4*)(out + idx) = s;
}

// ---------------- RoPE on q_exp (bf16, in place) ----------------
__global__ __launch_bounds__(256) void rope_q_kernel(
    bf16* __restrict__ qe, const int* __restrict__ pos_ids) {
  int row = blockIdx.x;
  int b = row >> 6, l = row & 63;
  float pos = (float)pos_ids[b * S_TOT + LV_ + l];
  bf16* qrow = qe + (size_t)row * HD_;
  for (int p = threadIdx.x; p < H_ * 64; p += 256) {
    int hh = p >> 6, i = p & 63;
    float inv_ts = expf(-9.210340371976184f * (float)i * (1.0f / 64.0f));
    float r = pos * inv_ts;
    float sn = sinf(r), cs = cosf(r);
    float x1 = b2f(qrow[hh * DH_ + i]), x2 = b2f(qrow[hh * DH_ + i + 64]);
    qrow[hh * DH_ + i]      = f2b(x1 * cs - x2 * sn);
    qrow[hh * DH_ + i + 64] = f2b(x2 * cs + x1 * sn);
  }
}

// ---------------- RoPE on K (bf16, in place in kbuf) ----------------
// grid: B_*S_TOT blocks; each handles KVH_*64 = 512 rotations
__global__ __launch_bounds__(256) void rope_k_inplace(
    bf16* __restrict__ kbuf, const int* __restrict__ pos_ids) {
  int s = blockIdx.x % S_TOT, b = blockIdx.x / S_TOT;
  float pos = (float)pos_ids[b * S_TOT + s];
  size_t base = ((size_t)(b * S_TOT + s)) * KVD_;
  for (int t = threadIdx.x; t < KVH_ * 64; t += 256) {
    int kvh = t >> 6, i = t & 63;
    size_t idx = base + kvh * DH_ + i;
    float inv_ts = expf(-9.210340371976184f * (float)i * (1.0f / 64.0f));
    float r = pos * inv_ts;
    float sn = sinf(r), cs = cosf(r);
    float x1 = b2f(kbuf[idx]), x2 = b2f(kbuf[idx + 64]);
    kbuf[idx]      = f2b(x1 * cs - x2 * sn);
    kbuf[idx + 64] = f2b(x2 * cs + x1 * sn);
  }
}

// ---------------- MFMA flash attention ----------------
// grid: 64 blocks = (b,h). 4 waves; wave w owns q rows w*16..w*16+15 (all 128 d).
// Loop 17 chunks of 64 keys: stage K row-major + V transposed in LDS,
// QK^T MFMA -> online softmax on C-frags -> P via LDS -> PV MFMA.
__global__ __launch_bounds__(256) void attn_mfma(
    const bf16* __restrict__ qe, const bf16* __restrict__ kbuf,
    const bf16* __restrict__ vbuf, bf16* __restrict__ attn_out) {
  int h = blockIdx.x & 31, b = blockIdx.x >> 5;
  int kvh = h >> 2;                      // G=4
  int tid = threadIdx.x;
  int lane = tid & 63, wid = tid >> 6;
  int lr = lane & 15, quad = lane >> 4;

  __shared__ ushort Ks[64][152];         // [key][d], pad 24 -> 19.0 KB
  __shared__ ushort vTs[128][72];        // [d][key], pad 8 -> 18.0 KB
  __shared__ ushort sc[4][16][72];       // per-wave P tile [q][key] -> 9.0 KB

  // Q A-fragments: lane holds Q[m=lr][k=quad*8+j], 4 k-steps of 32
  short8 qf[4];
  {
    const ushort* qptr = (const ushort*)qe +
        ((size_t)(b * LE_ + wid * 16 + lr)) * HD_ + h * DH_ + quad * 8;
#pragma unroll
    for (int ks = 0; ks < 4; ++ks) qf[ks] = *(const short8*)(qptr + ks * 32);
  }

  f32x4 Of[8] = {};                      // O C-frags: row=quad*4+r, col=lr+16*nt
  float m_i[4], l_i[4];
#pragma unroll
  for (int r = 0; r < 4; ++r) { m_i[r] = -1e30f; l_i[r] = 0.f; }

  const float scale = 0.08838834764831845f;   // 128^-0.5

  for (int c = 0; c < 17; ++c) {
    __syncthreads();
    // ---- stage K chunk (64 keys x 128 d), row-major ----
    {
      int dg = tid & 15, key0 = tid >> 4;     // 16 keys per iter
#pragma unroll
      for (int it = 0; it < 4; ++it) {
        int key = it * 16 + key0;
        short8 v = *(const short8*)((const ushort*)kbuf +
            ((size_t)(b * S_TOT + c * 64 + key) * KVH_ + kvh) * DH_ + dg * 8);
        *(short8*)&Ks[key][dg * 8] = v;
      }
    }
    // ---- stage V chunk transposed: vTs[d][key] ----
    {
      int key = tid & 63, dgrp = tid >> 6;    // 32 d per thread
      const ushort* vp = (const ushort*)vbuf +
          ((size_t)(b * S_TOT + c * 64 + key) * KVH_ + kvh) * DH_ + dgrp * 32;
#pragma unroll
      for (int q8 = 0; q8 < 4; ++q8) {
        short8 v = *(const short8*)(vp + q8 * 8);
#pragma unroll
        for (int j = 0; j < 8; ++j)
          vTs[dgrp * 32 + q8 * 8 + j][key] = (ushort)v[j];
      }
    }
    __syncthreads();

    // ---- QK^T: S (16q x 64k) in 4 C-frags ----
    f32x4 Sf[4] = {};
#pragma unroll
    for (int kt = 0; kt < 4; ++kt)
#pragma unroll
      for (int ks = 0; ks < 4; ++ks) {
        short8 kf = *(const short8*)&Ks[kt * 16 + lr][quad * 8 + ks * 32];
        Sf[kt] = __builtin_amdgcn_mfma_f32_16x16x32_bf16(qf[ks], kf, Sf[kt], 0, 0, 0);
      }

    // ---- online softmax (rows r -> q = quad*4+r) ----
#pragma unroll
    for (int kt = 0; kt < 4; ++kt) Sf[kt] *= scale;
#pragma unroll
    for (int r = 0; r < 4; ++r) {
      float mx = fmaxf(fmaxf(Sf[0][r], Sf[1][r]), fmaxf(Sf[2][r], Sf[3][r]));
#pragma unroll
      for (int msk = 1; msk < 16; msk <<= 1) mx = fmaxf(mx, __shfl_xor(mx, msk));
      float mn = fmaxf(m_i[r], mx);
      float alpha = __expf(m_i[r] - mn);
      m_i[r] = mn;
      float ls = 0.f;
#pragma unroll
      for (int kt = 0; kt < 4; ++kt) {
        float p = __expf(Sf[kt][r] - mn);
        Sf[kt][r] = p;
        ls += p;
      }
      l_i[r] = l_i[r] * alpha + ls;
#pragma unroll
      for (int nt = 0; nt < 8; ++nt) Of[nt][r] *= alpha;
      // write P row (bf16) into per-wave sc tile
#pragma unroll
      for (int kt = 0; kt < 4; ++kt) {
        bf16 t = f2b(Sf[kt][r]);
        sc[wid][quad * 4 + r][kt * 16 + lr] = *(ushort*)&t;
      }
    }

    // ---- PV: O += P (16x64) * V (64x128) ----
#pragma unroll
    for (int ks = 0; ks < 2; ++ks) {
      short8 pf = *(const short8*)&sc[wid][lr][quad * 8 + ks * 32];
#pragma unroll
      for (int nt = 0; nt < 8; ++nt) {
        short8 vf = *(const short8*)&vTs[nt * 16 + lr][quad * 8 + ks * 32];
        Of[nt] = __builtin_amdgcn_mfma_f32_16x16x32_bf16(pf, vf, Of[nt], 0, 0, 0);
      }
    }
  }

  // ---- finalize: reduce l across 16-lane row group, normalize, store ----
  float linv[4];
#pragma unroll
  for (int r = 0; r < 4; ++r) {
    float l = l_i[r];
#pragma unroll
    for (int msk = 1; msk < 16; msk <<= 1) l += __shfl_xor(l, msk);
    linv[r] = 1.f / l;
  }
  ushort* obase = (ushort*)attn_out + h * DH_;
#pragma unroll
  for (int nt = 0; nt < 8; ++nt)
#pragma unroll
    for (int r = 0; r < 4; ++r) {
      int q = wid * 16 + quad * 4 + r;
      bf16 t = f2b(Of[nt][r] * linv[r]);
      obase[((size_t)(b * LE_ + q)) * HD_ + nt * 16 + lr] = *(ushort*)&t;
    }
}

extern "C" void kernel_launch(void* const* d_in, const int* in_sizes, int n_in,
                              void* d_out, int out_size, void* d_ws, size_t ws_size,
                              hipStream_t stream) {
  const float* vlm      = (const float*)d_in[0];
  const float* expe     = (const float*)d_in[1];
  const int*   pos      = (const int*)d_in[2];
  // d_in[3] attention_mask: all-True -> unmasked softmax equivalent
  const float* w_ln_vlm = (const float*)d_in[4];
  // d_in[5] Wq_vlm unused (vlm queries don't affect expert outputs)
  const float* Wk_vlm   = (const float*)d_in[6];
  const float* Wv_vlm   = (const float*)d_in[7];
  // d_in[8] Wo_vlm unused
  const float* w_ln_exp = (const float*)d_in[9];
  const float* Wq_exp   = (const float*)d_in[10];
  const float* Wk_exp   = (const float*)d_in[11];
  const float* Wv_exp   = (const float*)d_in[12];
  const float* Wo_exp   = (const float*)d_in[13];
  float* out = (float*)d_out;
  char* ws = (char*)d_ws;

  bf16* hv_b  = (bf16*)(ws + OFF_HVB);
  bf16* WkvT  = (bf16*)(ws + OFF_WKVT);
  bf16* he_b  = (bf16*)(ws + OFF_HEB);
  bf16* WqkvT = (bf16*)(ws + OFF_WQKVT);
  bf16* qe    = (bf16*)(ws + OFF_QE);
  bf16* kbuf  = (bf16*)(ws + OFF_KBUF);
  bf16* vbuf  = (bf16*)(ws + OFF_VBUF);
  bf16* ao    = (bf16*)(ws + OFF_AO);
  float* part1 = (float*)(ws + OFF_P1);
  bf16* WoT   = (bf16*)(ws + OFF_WOT);
  float* part2 = (float*)(ws + OFF_P2);

  // 1) RMSNorm -> bf16
  rmsnorm_bf16<<<B_ * LV_, 256, 0, stream>>>(vlm, w_ln_vlm, hv_b, DV_);
  rmsnorm_bf16<<<B_ * LE_, 256, 0, stream>>>(expe, w_ln_exp, he_b, DE_);

  // 2) weight transpose-converts
  tconv<<<dim3(16, 40), 256, 0, stream>>>(Wk_vlm, WkvT, DV_, KVD_, 0);
  tconv<<<dim3(16, 40), 256, 0, stream>>>(Wv_vlm, WkvT, DV_, KVD_, 1024);
  tconv<<<dim3(64, 30), 256, 0, stream>>>(Wq_exp, WqkvT, DE_, HD_, 0);
  tconv<<<dim3(16, 30), 256, 0, stream>>>(Wk_exp, WqkvT, DE_, KVD_, 4096);
  tconv<<<dim3(16, 30), 256, 0, stream>>>(Wv_exp, WqkvT, DE_, KVD_, 5120);

  // 3) big GEMM: vlm K/V projections (M=2048, N=2048, K=2560)
  gemm_mfma<<<dim3(16, 16), 256, 0, stream>>>(hv_b, WkvT, 2048, 2048, DV_,
                                              kbuf, vbuf);

  // 4) expert QKV GEMM, split-K (M=128, N=6144, K=1920, 6 splits of 320)
  gemm_splitk<<<dim3(48, NSPLIT1), 256, 0, stream>>>(he_b, WqkvT, 6144, DE_,
                                                     DE_ / NSPLIT1, part1);
  reduce_qkv<<<128 * 6144 / 4 / 256, 256, 0, stream>>>(part1, qe, kbuf, vbuf);

  // 5) RoPE (Q in qe; K in place in kbuf)
  rope_q_kernel<<<B_ * LE_, 256, 0, stream>>>(qe, pos);
  rope_k_inplace<<<B_ * S_TOT, 256, 0, stream>>>(kbuf, pos);

  // 6) Wo transpose-convert into region freed after reduce1
  tconv<<<dim3(30, 64), 256, 0, stream>>>(Wo_exp, WoT, HD_, DE_, 0);

  // 7) MFMA flash attention (expert queries only)
  attn_mfma<<<B_ * H_, 256, 0, stream>>>(qe, kbuf, vbuf, ao);

  // 8) output projection, split-K (M=128, N=1920, K=4096, 16 splits of 256)
  gemm_splitk<<<dim3(15, NSPLIT2), 256, 0, stream>>>(ao, WoT, 1920, HD_,
                                                     HD_ / NSPLIT2, part2);
  reduce_out<<<128 * 1920 / 4 / 256, 256, 0, stream>>>(part2, expe, out);
}

// Round 6
// 342.003 us; speedup vs baseline: 1.1739x; 1.1739x over previous
//
#include <hip/hip_runtime.h>
#include <hip/hip_bf16.h>
#include <cstddef>

// Problem constants
#define B_  2
#define LV_ 1024
#define LE_ 64
#define S_TOT 1088          // LV+LE
#define DV_ 2560
#define DE_ 1920
#define H_  32
#define KVH_ 8
#define DH_ 128
#define HD_ 4096            // H*DH
#define KVD_ 1024           // KVH*DH
#define NSPL 9              // attention key splits (8x128 + 1x64)

typedef short short8 __attribute__((ext_vector_type(8)));
typedef float f32x4 __attribute__((ext_vector_type(4)));

typedef __hip_bfloat16 bf16;

__device__ inline float b2f(bf16 h) { return __bfloat162float(h); }
__device__ inline bf16 f2b(float f) { return __float2bfloat16(f); }

// ---------------- Workspace layout (byte offsets) ----------------
// hv_b   : 2048x2560 bf16 @ 0           (10,485,760)
// WkvT   : 2048x2560 bf16 @ 10,485,760  (10,485,760)
// he_b   : 128x1920 bf16  @ 20,971,520  (491,520)
// WqkvT  : 6144x1920 bf16 @ 21,463,040  (23,592,960)
// qe     : 128x4096 bf16  @ 45,056,000  (1,048,576)
// kbuf   : 2x1088x1024    @ 46,104,576  (4,456,448)
// vbuf   : 2x1088x1024    @ 50,561,024  (4,456,448)
// ao     : 128x4096 bf16  @ 59,473,920  (1,048,576)
// Aliases (stream-ordered lifetimes):
//  part1 : 6x128x6144 f32 (18.9MB) @ 0          (hv_b+WkvT dead after big gemm)
//  WoT   : 1920x4096 bf16 (15.7MB) @ 0          (part1 dead after reduce_qkv)
//  m_arr : 9x4096 f32 @ 20,971,520  } alias he_b (dead after splitk1)
//  l_arr : 9x4096 f32 @ 21,118,976  }
//  O_p   : 9x4096x128 f32 (18.9MB) @ 21,463,040 (WqkvT dead after splitk1)
//  part2 : 16x128x1920 f32 (15.7MB) @ 21,463,040 (O_p dead after combine)
#define OFF_HVB   0ul
#define OFF_WKVT  10485760ul
#define OFF_HEB   20971520ul
#define OFF_WQKVT 21463040ul
#define OFF_QE    45056000ul
#define OFF_KBUF  46104576ul
#define OFF_VBUF  50561024ul
#define OFF_AO    59473920ul
#define OFF_P1    0ul
#define OFF_WOT   0ul
#define OFF_M     20971520ul
#define OFF_L     21118976ul
#define OFF_OP    21463040ul
#define OFF_P2    21463040ul

#define NSPLIT1 6
#define NSPLIT2 16

// ---------------- RMSNorm -> bf16 ----------------
__global__ __launch_bounds__(256) void rmsnorm_bf16(
    const float* __restrict__ x, const float* __restrict__ w,
    bf16* __restrict__ out, int D) {
  int row = blockIdx.x;
  const float4* x4 = (const float4*)(x + (size_t)row * D);
  const float4* w4 = (const float4*)w;
  int D4 = D >> 2;
  float ss = 0.f;
  for (int i = threadIdx.x; i < D4; i += 256) {
    float4 v = x4[i];
    ss += v.x * v.x + v.y * v.y + v.z * v.z + v.w * v.w;
  }
  __shared__ float red[256];
  red[threadIdx.x] = ss; __syncthreads();
  for (int s = 128; s > 0; s >>= 1) {
    if (threadIdx.x < s) red[threadIdx.x] += red[threadIdx.x + s];
    __syncthreads();
  }
  float inv = rsqrtf(red[0] / (float)D + 1e-6f);
  ushort4* o4 = (ushort4*)(out + (size_t)row * D);
  for (int i = threadIdx.x; i < D4; i += 256) {
    float4 v = x4[i], wv = w4[i];
    bf16 a = f2b(v.x * inv * wv.x), b = f2b(v.y * inv * wv.y);
    bf16 c = f2b(v.z * inv * wv.z), d = f2b(v.w * inv * wv.w);
    ushort4 o;
    o.x = *(ushort*)&a; o.y = *(ushort*)&b; o.z = *(ushort*)&c; o.w = *(ushort*)&d;
    o4[i] = o;
  }
}

// ---------------- 64x64 transpose-convert tile helper ----------------
__device__ inline void tile_tconv(float (*t)[65],
    const float* __restrict__ W, bf16* __restrict__ Wt,
    int K, int N, int n_off, int bx, int by) {
  int n0 = bx * 64, k0 = by * 64;
  int tid = threadIdx.x;
  int c = tid & 63, r4 = tid >> 6;
#pragma unroll 4
  for (int it = 0; it < 16; ++it) {
    int k = it * 4 + r4;
    t[k][c] = W[(size_t)(k0 + k) * N + n0 + c];
  }
  __syncthreads();
#pragma unroll 4
  for (int it = 0; it < 16; ++it) {
    int n = it * 4 + r4;
    Wt[(size_t)(n_off + n0 + n) * K + k0 + c] = f2b(t[c][n]);
  }
}

// generic single-matrix version (used for WoT)
__global__ __launch_bounds__(256) void tconv(
    const float* __restrict__ W, bf16* __restrict__ Wt,
    int K, int N, int n_off) {
  __shared__ float t[64][65];
  tile_tconv(t, W, Wt, K, N, n_off, blockIdx.x, blockIdx.y);
}

// fused: all 5 pre-GEMM weight converts in one dispatch (4160 blocks)
__global__ __launch_bounds__(256) void tconv_all(
    const float* __restrict__ Wk_vlm, const float* __restrict__ Wv_vlm,
    const float* __restrict__ Wq_exp, const float* __restrict__ Wk_exp,
    const float* __restrict__ Wv_exp,
    bf16* __restrict__ WkvT, bf16* __restrict__ WqkvT) {
  __shared__ float t[64][65];
  int id = blockIdx.x;
  if (id < 640)       tile_tconv(t, Wk_vlm, WkvT, DV_, KVD_, 0,    id % 16, id / 16);
  else if (id < 1280) { id -= 640;  tile_tconv(t, Wv_vlm, WkvT,  DV_, KVD_, 1024, id % 16, id / 16); }
  else if (id < 3200) { id -= 1280; tile_tconv(t, Wq_exp, WqkvT, DE_, HD_,  0,    id % 64, id / 64); }
  else if (id < 3680) { id -= 3200; tile_tconv(t, Wk_exp, WqkvT, DE_, KVD_, 4096, id % 16, id / 16); }
  else                { id -= 3680; tile_tconv(t, Wv_exp, WqkvT, DE_, KVD_, 5120, id % 16, id / 16); }
}

// ---------------- bf16 MFMA GEMM (big): C = A(MxK) * Bt(NxK)^T ----------------
__global__ __launch_bounds__(256) void gemm_mfma(
    const bf16* __restrict__ A, const bf16* __restrict__ Bt,
    int M, int N, int K,
    bf16* __restrict__ p_k, bf16* __restrict__ p_v) {
  __shared__ ushort As[128][40];
  __shared__ ushort Bs[128][40];
  int tid = threadIdx.x;
  int lane = tid & 63, wid = tid >> 6;
  int wm = (wid >> 1) * 64, wn = (wid & 1) * 64;
  int m0 = blockIdx.y * 128, n0 = blockIdx.x * 128;
  int lrow = lane & 15, quad = lane >> 4;

  f32x4 acc[4][4] = {};

  int ar = tid >> 2;            // 0..63
  int ac = (tid & 3) * 8;       // 0,8,16,24
  const ushort* Aptr = (const ushort*)A + (size_t)(m0 + ar) * K + ac;
  const ushort* Bptr = (const ushort*)Bt + (size_t)(n0 + ar) * K + ac;

  for (int k0 = 0; k0 < K; k0 += 32) {
    short8 a0 = *(const short8*)(Aptr + k0);
    short8 a1 = *(const short8*)(Aptr + (size_t)64 * K + k0);
    short8 b0 = *(const short8*)(Bptr + k0);
    short8 b1 = *(const short8*)(Bptr + (size_t)64 * K + k0);
    __syncthreads();
    *(short8*)&As[ar][ac] = a0;
    *(short8*)&As[64 + ar][ac] = a1;
    *(short8*)&Bs[ar][ac] = b0;
    *(short8*)&Bs[64 + ar][ac] = b1;
    __syncthreads();
    short8 af[4], bfr[4];
#pragma unroll
    for (int i = 0; i < 4; ++i) {
      af[i]  = *(const short8*)&As[wm + i * 16 + lrow][quad * 8];
      bfr[i] = *(const short8*)&Bs[wn + i * 16 + lrow][quad * 8];
    }
#pragma unroll
    for (int i = 0; i < 4; ++i)
#pragma unroll
      for (int j = 0; j < 4; ++j)
        acc[i][j] = __builtin_amdgcn_mfma_f32_16x16x32_bf16(af[i], bfr[j], acc[i][j], 0, 0, 0);
  }

#pragma unroll
  for (int i = 0; i < 4; ++i) {
    int gm_base = m0 + wm + i * 16 + quad * 4;
#pragma unroll
    for (int j = 0; j < 4; ++j) {
      int gn = n0 + wn + j * 16 + lrow;
#pragma unroll
      for (int r = 0; r < 4; ++r) {
        int m = gm_base + r;
        float v = acc[i][j][r];
        int b = m >> 10, s = m & 1023;
        size_t row = (size_t)(b * S_TOT + s);
        if (gn < 1024) p_k[row * KVD_ + gn] = f2b(v);
        else           p_v[row * KVD_ + (gn - 1024)] = f2b(v);
      }
    }
  }
}

// ---------------- Split-K MFMA GEMM for M=128 skinny GEMMs ----------------
__global__ __launch_bounds__(256) void gemm_splitk(
    const bf16* __restrict__ A, const bf16* __restrict__ Bt,
    int N, int K_full, int Kc, float* __restrict__ partial) {
  __shared__ ushort As[128][40];
  __shared__ ushort Bs[128][40];
  int tid = threadIdx.x;
  int lane = tid & 63, wid = tid >> 6;
  int wm = (wid >> 1) * 64, wn = (wid & 1) * 64;
  int n0 = blockIdx.x * 128;
  int k_beg = blockIdx.y * Kc, k_end = k_beg + Kc;
  int lrow = lane & 15, quad = lane >> 4;

  f32x4 acc[4][4] = {};

  int ar = tid >> 2;
  int ac = (tid & 3) * 8;
  const ushort* Aptr = (const ushort*)A + (size_t)ar * K_full + ac;
  const ushort* Bptr = (const ushort*)Bt + (size_t)(n0 + ar) * K_full + ac;

  for (int k0 = k_beg; k0 < k_end; k0 += 32) {
    short8 a0 = *(const short8*)(Aptr + k0);
    short8 a1 = *(const short8*)(Aptr + (size_t)64 * K_full + k0);
    short8 b0 = *(const short8*)(Bptr + k0);
    short8 b1 = *(const short8*)(Bptr + (size_t)64 * K_full + k0);
    __syncthreads();
    *(short8*)&As[ar][ac] = a0;
    *(short8*)&As[64 + ar][ac] = a1;
    *(short8*)&Bs[ar][ac] = b0;
    *(short8*)&Bs[64 + ar][ac] = b1;
    __syncthreads();
    short8 af[4], bfr[4];
#pragma unroll
    for (int i = 0; i < 4; ++i) {
      af[i]  = *(const short8*)&As[wm + i * 16 + lrow][quad * 8];
      bfr[i] = *(const short8*)&Bs[wn + i * 16 + lrow][quad * 8];
    }
#pragma unroll
    for (int i = 0; i < 4; ++i)
#pragma unroll
      for (int j = 0; j < 4; ++j)
        acc[i][j] = __builtin_amdgcn_mfma_f32_16x16x32_bf16(af[i], bfr[j], acc[i][j], 0, 0, 0);
  }

  float* pbase = partial + (size_t)blockIdx.y * 128 * N;
#pragma unroll
  for (int i = 0; i < 4; ++i) {
    int m_base = wm + i * 16 + quad * 4;
#pragma unroll
    for (int j = 0; j < 4; ++j) {
      int gn = n0 + wn + j * 16 + lrow;
#pragma unroll
      for (int r = 0; r < 4; ++r)
        pbase[(size_t)(m_base + r) * N + gn] = acc[i][j][r];
    }
  }
}

// ---------------- Reduce split-K partials: expert QKV (N=6144) ----------------
__global__ __launch_bounds__(256) void reduce_qkv(
    const float* __restrict__ partial, bf16* __restrict__ qe,
    bf16* __restrict__ kbuf, bf16* __restrict__ vbuf) {
  int idx = (blockIdx.x * 256 + threadIdx.x) * 4;   // over 128*6144
  int m = idx / 6144, n = idx % 6144;
  f32x4 s = {};
#pragma unroll
  for (int sp = 0; sp < NSPLIT1; ++sp) {
    const f32x4 v = *(const f32x4*)(partial + (size_t)sp * 128 * 6144 + idx);
    s += v;
  }
  ushort4 o;
  bf16 h0 = f2b(s[0]), h1 = f2b(s[1]), h2 = f2b(s[2]), h3 = f2b(s[3]);
  o.x = *(ushort*)&h0; o.y = *(ushort*)&h1; o.z = *(ushort*)&h2; o.w = *(ushort*)&h3;
  int b = m >> 6, l = m & 63;
  if (n < 4096) {
    *(ushort4*)((ushort*)qe + (size_t)m * HD_ + n) = o;
  } else {
    size_t row = (size_t)(b * S_TOT + LV_ + l);
    if (n < 5120) *(ushort4*)((ushort*)kbuf + row * KVD_ + (n - 4096)) = o;
    else          *(ushort4*)((ushort*)vbuf + row * KVD_ + (n - 5120)) = o;
  }
}

// ---------------- Reduce split-K partials + residual: output (N=1920) ----------------
__global__ __launch_bounds__(256) void reduce_out(
    const float* __restrict__ partial, const float* __restrict__ residual,
    float* __restrict__ out) {
  int idx = (blockIdx.x * 256 + threadIdx.x) * 4;   // over 128*1920
  f32x4 s = *(const f32x4*)(residual + idx);
#pragma unroll
  for (int sp = 0; sp < NSPLIT2; ++sp) {
    const f32x4 v = *(const f32x4*)(partial + (size_t)sp * 128 * 1920 + idx);
    s += v;
  }
  *(f32x4*)(out + idx) = s;
}

// ---------------- Fused RoPE: Q (blocks 0..127) and K in-place (rest) ----------------
__global__ __launch_bounds__(256) void rope_fused(
    bf16* __restrict__ qe, bf16* __restrict__ kbuf,
    const int* __restrict__ pos_ids) {
  if (blockIdx.x < 128) {
    int row = blockIdx.x;
    int b = row >> 6, l = row & 63;
    float pos = (float)pos_ids[b * S_TOT + LV_ + l];
    bf16* qrow = qe + (size_t)row * HD_;
    for (int p = threadIdx.x; p < H_ * 64; p += 256) {
      int hh = p >> 6, i = p & 63;
      float inv_ts = expf(-9.210340371976184f * (float)i * (1.0f / 64.0f));
      float r = pos * inv_ts;
      float sn = sinf(r), cs = cosf(r);
      float x1 = b2f(qrow[hh * DH_ + i]), x2 = b2f(qrow[hh * DH_ + i + 64]);
      qrow[hh * DH_ + i]      = f2b(x1 * cs - x2 * sn);
      qrow[hh * DH_ + i + 64] = f2b(x2 * cs + x1 * sn);
    }
  } else {
    int bid = blockIdx.x - 128;
    int s = bid % S_TOT, b = bid / S_TOT;
    float pos = (float)pos_ids[b * S_TOT + s];
    size_t base = ((size_t)(b * S_TOT + s)) * KVD_;
    for (int t = threadIdx.x; t < KVH_ * 64; t += 256) {
      int kvh = t >> 6, i = t & 63;
      size_t idx = base + kvh * DH_ + i;
      float inv_ts = expf(-9.210340371976184f * (float)i * (1.0f / 64.0f));
      float r = pos * inv_ts;
      float sn = sinf(r), cs = cosf(r);
      float x1 = b2f(kbuf[idx]), x2 = b2f(kbuf[idx + 64]);
      kbuf[idx]      = f2b(x1 * cs - x2 * sn);
      kbuf[idx + 64] = f2b(x2 * cs + x1 * sn);
    }
  }
}

// ---------------- MFMA flash attention, split over keys ----------------
// grid: 576 = (b,h) x 9 splits. Splits 0..7: 128 keys (2 chunks); split 8: 64.
// Writes unnormalized partial O (f32) + chunk-local m,l per q row.
__global__ __launch_bounds__(256) void attn_part(
    const bf16* __restrict__ qe, const bf16* __restrict__ kbuf,
    const bf16* __restrict__ vbuf,
    float* __restrict__ O_p, float* __restrict__ m_arr,
    float* __restrict__ l_arr) {
  int bh = blockIdx.x & 63;              // (b<<5)|h
  int split = blockIdx.x >> 6;           // 0..8
  int h = bh & 31, b = bh >> 5;
  int kvh = h >> 2;                      // G=4
  int tid = threadIdx.x;
  int lane = tid & 63, wid = tid >> 6;
  int lr = lane & 15, quad = lane >> 4;

  __shared__ ushort Ks[64][152];
  __shared__ ushort vTs[128][72];
  __shared__ ushort sc[4][16][72];

  // Q A-fragments: lane holds Q[m=lr][k=quad*8+j], 4 k-steps of 32
  short8 qf[4];
  {
    const ushort* qptr = (const ushort*)qe +
        ((size_t)(b * LE_ + wid * 16 + lr)) * HD_ + h * DH_ + quad * 8;
#pragma unroll
    for (int ks = 0; ks < 4; ++ks) qf[ks] = *(const short8*)(qptr + ks * 32);
  }

  f32x4 Of[8] = {};                      // O C-frags: row=quad*4+r, col=lr+16*nt
  float m_i[4], l_i[4];
#pragma unroll
  for (int r = 0; r < 4; ++r) { m_i[r] = -1e30f; l_i[r] = 0.f; }

  const float scale = 0.08838834764831845f;   // 128^-0.5
  int nch = (split == 8) ? 1 : 2;

  for (int c = 0; c < nch; ++c) {
    int key0 = split * 128 + c * 64;
    __syncthreads();
    // ---- stage K chunk (64 keys x 128 d), row-major ----
    {
      int dg = tid & 15, kq = tid >> 4;       // 16 keys per iter
#pragma unroll
      for (int it = 0; it < 4; ++it) {
        int key = it * 16 + kq;
        short8 v = *(const short8*)((const ushort*)kbuf +
            ((size_t)(b * S_TOT + key0 + key) * KVH_ + kvh) * DH_ + dg * 8);
        *(short8*)&Ks[key][dg * 8] = v;
      }
    }
    // ---- stage V chunk transposed: vTs[d][key] ----
    {
      int key = tid & 63, dgrp = tid >> 6;
      const ushort* vp = (const ushort*)vbuf +
          ((size_t)(b * S_TOT + key0 + key) * KVH_ + kvh) * DH_ + dgrp * 32;
      short8 vv[4];
#pragma unroll
      for (int q8 = 0; q8 < 4; ++q8) vv[q8] = *(const short8*)(vp + q8 * 8);
#pragma unroll
      for (int q8 = 0; q8 < 4; ++q8)
#pragma unroll
        for (int j = 0; j < 8; ++j)
          vTs[dgrp * 32 + q8 * 8 + j][key] = (ushort)vv[q8][j];
    }
    __syncthreads();

    // ---- QK^T: S (16q x 64k) in 4 C-frags ----
    f32x4 Sf[4] = {};
#pragma unroll
    for (int kt = 0; kt < 4; ++kt)
#pragma unroll
      for (int ks = 0; ks < 4; ++ks) {
        short8 kf = *(const short8*)&Ks[kt * 16 + lr][quad * 8 + ks * 32];
        Sf[kt] = __builtin_amdgcn_mfma_f32_16x16x32_bf16(qf[ks], kf, Sf[kt], 0, 0, 0);
      }

    // ---- online softmax (rows r -> q = quad*4+r) ----
#pragma unroll
    for (int kt = 0; kt < 4; ++kt) Sf[kt] *= scale;
#pragma unroll
    for (int r = 0; r < 4; ++r) {
      float mx = fmaxf(fmaxf(Sf[0][r], Sf[1][r]), fmaxf(Sf[2][r], Sf[3][r]));
#pragma unroll
      for (int msk = 1; msk < 16; msk <<= 1) mx = fmaxf(mx, __shfl_xor(mx, msk));
      float mn = fmaxf(m_i[r], mx);
      float alpha = __expf(m_i[r] - mn);
      m_i[r] = mn;
      float ls = 0.f;
#pragma unroll
      for (int kt = 0; kt < 4; ++kt) {
        float p = __expf(Sf[kt][r] - mn);
        Sf[kt][r] = p;
        ls += p;
      }
      l_i[r] = l_i[r] * alpha + ls;
#pragma unroll
      for (int nt = 0; nt < 8; ++nt) Of[nt][r] *= alpha;
#pragma unroll
      for (int kt = 0; kt < 4; ++kt) {
        bf16 t = f2b(Sf[kt][r]);
        sc[wid][quad * 4 + r][kt * 16 + lr] = *(ushort*)&t;
      }
    }

    // ---- PV: O += P (16x64) * V (64x128) ----
#pragma unroll
    for (int ks = 0; ks < 2; ++ks) {
      short8 pf = *(const short8*)&sc[wid][lr][quad * 8 + ks * 32];
#pragma unroll
      for (int nt = 0; nt < 8; ++nt) {
        short8 vf = *(const short8*)&vTs[nt * 16 + lr][quad * 8 + ks * 32];
        Of[nt] = __builtin_amdgcn_mfma_f32_16x16x32_bf16(pf, vf, Of[nt], 0, 0, 0);
      }
    }
  }

  // ---- finalize l: per-lane l_i covers only cols {lr,16+lr,32+lr,48+lr};
  //      sum across the 16-lane lr group for the true row sum (BUGFIX r5) ----
  float l_row[4];
#pragma unroll
  for (int r = 0; r < 4; ++r) {
    float l = l_i[r];
#pragma unroll
    for (int msk = 1; msk < 16; msk <<= 1) l += __shfl_xor(l, msk);
    l_row[r] = l;
  }

  // ---- write partials: O_p[(split*4096 + row)*128 + d], row=(b*32+h)*64+q ----
  size_t rbase = (size_t)split * 4096 + (size_t)bh * 64;
#pragma unroll
  for (int nt = 0; nt < 8; ++nt)
#pragma unroll
    for (int r = 0; r < 4; ++r) {
      int q = wid * 16 + quad * 4 + r;
      O_p[(rbase + q) * 128 + nt * 16 + lr] = Of[nt][r];
    }
  if (lr == 0) {
#pragma unroll
    for (int r = 0; r < 4; ++r) {
      int q = wid * 16 + quad * 4 + r;
      m_arr[rbase + q] = m_i[r];
      l_arr[rbase + q] = l_row[r];
    }
  }
}

// ---------------- Combine attention splits -> ao (bf16) ----------------
__global__ __launch_bounds__(256) void attn_combine(
    const float* __restrict__ O_p, const float* __restrict__ m_arr,
    const float* __restrict__ l_arr, bf16* __restrict__ ao) {
  int t = blockIdx.x * 256 + threadIdx.x;    // over 4096*128
  int d = t & 127, row = t >> 7;             // row=(b*32+h)*64+q
  float m_g = -1e30f;
#pragma unroll
  for (int s = 0; s < NSPL; ++s) m_g = fmaxf(m_g, m_arr[s * 4096 + row]);
  float denom = 0.f, acc = 0.f;
#pragma unroll
  for (int s = 0; s < NSPL; ++s) {
    float w = __expf(m_arr[s * 4096 + row] - m_g);
    denom += w * l_arr[s * 4096 + row];
    acc   += w * O_p[((size_t)s * 4096 + row) * 128 + d];
  }
  int b = row >> 11, h = (row >> 6) & 31, q = row & 63;
  bf16 o = f2b(acc / denom);
  ((ushort*)ao)[((size_t)(b * 64 + q) * 32 + h) * 128 + d] = *(ushort*)&o;
}

extern "C" void kernel_launch(void* const* d_in, const int* in_sizes, int n_in,
                              void* d_out, int out_size, void* d_ws, size_t ws_size,
                              hipStream_t stream) {
  const float* vlm      = (const float*)d_in[0];
  const float* expe     = (const float*)d_in[1];
  const int*   pos      = (const int*)d_in[2];
  // d_in[3] attention_mask: all-True -> unmasked softmax equivalent
  const float* w_ln_vlm = (const float*)d_in[4];
  // d_in[5] Wq_vlm unused (vlm queries don't affect expert outputs)
  const float* Wk_vlm   = (const float*)d_in[6];
  const float* Wv_vlm   = (const float*)d_in[7];
  // d_in[8] Wo_vlm unused
  const float* w_ln_exp = (const float*)d_in[9];
  const float* Wq_exp   = (const float*)d_in[10];
  const float* Wk_exp   = (const float*)d_in[11];
  const float* Wv_exp   = (const float*)d_in[12];
  const float* Wo_exp   = (const float*)d_in[13];
  float* out = (float*)d_out;
  char* ws = (char*)d_ws;

  bf16* hv_b  = (bf16*)(ws + OFF_HVB);
  bf16* WkvT  = (bf16*)(ws + OFF_WKVT);
  bf16* he_b  = (bf16*)(ws + OFF_HEB);
  bf16* WqkvT = (bf16*)(ws + OFF_WQKVT);
  bf16* qe    = (bf16*)(ws + OFF_QE);
  bf16* kbuf  = (bf16*)(ws + OFF_KBUF);
  bf16* vbuf  = (bf16*)(ws + OFF_VBUF);
  bf16* ao    = (bf16*)(ws + OFF_AO);
  float* part1 = (float*)(ws + OFF_P1);
  bf16* WoT   = (bf16*)(ws + OFF_WOT);
  float* m_arr = (float*)(ws + OFF_M);
  float* l_arr = (float*)(ws + OFF_L);
  float* O_p   = (float*)(ws + OFF_OP);
  float* part2 = (float*)(ws + OFF_P2);

  // 1) RMSNorm -> bf16
  rmsnorm_bf16<<<B_ * LV_, 256, 0, stream>>>(vlm, w_ln_vlm, hv_b, DV_);
  rmsnorm_bf16<<<B_ * LE_, 256, 0, stream>>>(expe, w_ln_exp, he_b, DE_);

  // 2) all pre-GEMM weight transpose-converts, one dispatch
  tconv_all<<<4160, 256, 0, stream>>>(Wk_vlm, Wv_vlm, Wq_exp, Wk_exp, Wv_exp,
                                      WkvT, WqkvT);

  // 3) big GEMM: vlm K/V projections (M=2048, N=2048, K=2560)
  gemm_mfma<<<dim3(16, 16), 256, 0, stream>>>(hv_b, WkvT, 2048, 2048, DV_,
                                              kbuf, vbuf);

  // 4) expert QKV GEMM, split-K (M=128, N=6144, K=1920, 6 splits of 320)
  gemm_splitk<<<dim3(48, NSPLIT1), 256, 0, stream>>>(he_b, WqkvT, 6144, DE_,
                                                     DE_ / NSPLIT1, part1);
  reduce_qkv<<<128 * 6144 / 4 / 256, 256, 0, stream>>>(part1, qe, kbuf, vbuf);

  // 5) RoPE (Q + K in-place), one dispatch
  rope_fused<<<128 + B_ * S_TOT, 256, 0, stream>>>(qe, kbuf, pos);

  // 6) Wo transpose-convert into region freed after reduce_qkv
  tconv<<<dim3(30, 64), 256, 0, stream>>>(Wo_exp, WoT, HD_, DE_, 0);

  // 7) flash attention, 9 key-splits -> partials, then combine
  attn_part<<<64 * NSPL, 256, 0, stream>>>(qe, kbuf, vbuf, O_p, m_arr, l_arr);
  attn_combine<<<4096 * 128 / 256, 256, 0, stream>>>(O_p, m_arr, l_arr, ao);

  // 8) output projection, split-K (M=128, N=1920, K=4096, 16 splits of 256)
  gemm_splitk<<<dim3(15, NSPLIT2), 256, 0, stream>>>(ao, WoT, 1920, HD_,
                                                     HD_ / NSPLIT2, part2);
  reduce_out<<<128 * 1920 / 4 / 256, 256, 0, stream>>>(part2, expe, out);
}